// Round 1
// baseline (1017.827 us; speedup 1.0000x reference)
//
#include <hip/hip_runtime.h>

#define N 768
#define D 128
#define NSQ (N*N)
#define EPS 1e-5f

typedef __bf16 bf16;
typedef __bf16 bf16x8 __attribute__((ext_vector_type(8)));
typedef float f32x4 __attribute__((ext_vector_type(4)));

__device__ __forceinline__ void gld16(const void* g, void* l) {
    __builtin_amdgcn_global_load_lds(
        (const __attribute__((address_space(1))) unsigned int*)g,
        (__attribute__((address_space(3))) unsigned int*)l, 16, 0, 0);
}

// ---------------- K0: convert 6 weight matrices fp32 -> bf16 ----------------
__global__ void k_convert_w(const float* __restrict__ lp, const float* __restrict__ lg,
                            const float* __restrict__ rp, const float* __restrict__ rg,
                            const float* __restrict__ op, const float* __restrict__ og,
                            bf16* __restrict__ dst) {
    const float* srcs[6] = {lp, lg, rp, rg, op, og};
    int m = blockIdx.y;
    int i = blockIdx.x * 256 + threadIdx.x;   // 64 blocks x 256 = 16384
    dst[m * 16384 + i] = (bf16)srcs[m][i];
}

// ---------------- K1: LN(pair) -> dual GEMM (proj & gate) -> sigmoid gate ----
// -> transposed store to {left_t|right_t}[d][row]
// A-operand = weights [128 d][128 k] (so C rows = d, coalesced transposed store)
// B^T-operand = z rows [64 r][128 k]
__global__ __launch_bounds__(256, 2) void k_ln_gate(
    const float* __restrict__ pair, const float* __restrict__ lnw, const float* __restrict__ lnb,
    const bf16* __restrict__ wbf,
    const float* __restrict__ lp_b, const float* __restrict__ lg_b,
    const float* __restrict__ rp_b, const float* __restrict__ rg_b,
    bf16* __restrict__ left_t, bf16* __restrict__ right_t)
{
    __shared__ bf16 zt[64 * 128];     // 16 KB, xor-swizzled chunks
    __shared__ bf16 wP[128 * 128];    // 32 KB
    __shared__ bf16 wG[128 * 128];    // 32 KB   total 80 KB -> 2 blocks/CU

    const int t = threadIdx.x;
    const int side = blockIdx.y;
    const int row0 = blockIdx.x * 64;

    const bf16* wPsrc = wbf + (side ? 2 : 0) * 16384;
    const bf16* wGsrc = wbf + (side ? 3 : 1) * 16384;
    const float* bPsrc = side ? rp_b : lp_b;
    const float* bGsrc = side ? rg_b : lg_b;
    bf16* dst = side ? right_t : left_t;

    // stage weights (pre-swizzled global source, linear LDS dest)
    #pragma unroll
    for (int c = 0; c < 8; ++c) {
        int s = c * 256 + t;               // 2048 slots of 16B per matrix
        int r = s >> 4, cp = s & 15, cl = cp ^ (r & 7);
        gld16(wPsrc + r * 128 + cl * 8, (char*)wP + s * 16);
        gld16(wGsrc + r * 128 + cl * 8, (char*)wG + s * 16);
    }

    // z-tile: layernorm of 64 pair rows, 4 threads/row
    {
        int r = t >> 2, q = t & 3;
        const float* prow = pair + (size_t)(row0 + r) * 128 + q * 32;
        float x[32];
        #pragma unroll
        for (int h = 0; h < 8; ++h) {
            f32x4 v = *(const f32x4*)(prow + h * 4);
            x[h*4+0] = v[0]; x[h*4+1] = v[1]; x[h*4+2] = v[2]; x[h*4+3] = v[3];
        }
        float s1 = 0.f, s2 = 0.f;
        #pragma unroll
        for (int j = 0; j < 32; ++j) { s1 += x[j]; s2 += x[j] * x[j]; }
        s1 += __shfl_xor(s1, 1); s2 += __shfl_xor(s2, 1);
        s1 += __shfl_xor(s1, 2); s2 += __shfl_xor(s2, 2);
        float mean = s1 * (1.f / 128.f);
        float rstd = rsqrtf(s2 * (1.f / 128.f) - mean * mean + EPS);
        #pragma unroll
        for (int cc = 0; cc < 4; ++cc) {
            bf16x8 pk;
            #pragma unroll
            for (int hh = 0; hh < 2; ++hh) {
                f32x4 wv = *(const f32x4*)(lnw + q * 32 + cc * 8 + hh * 4);
                f32x4 bv = *(const f32x4*)(lnb + q * 32 + cc * 8 + hh * 4);
                #pragma unroll
                for (int e = 0; e < 4; ++e) {
                    int j = cc * 8 + hh * 4 + e;
                    pk[hh * 4 + e] = (bf16)((x[j] - mean) * rstd * wv[e] + bv[e]);
                }
            }
            int cl = q * 4 + cc;
            *(bf16x8*)((char*)zt + r * 256 + (cl ^ (r & 7)) * 16) = pk;
        }
    }
    __syncthreads();

    const int lane = t & 63, wid = t >> 6;
    const int wd = wid & 1, wr2 = wid >> 1;
    const int lr = lane & 15, lh = lane >> 4;

    f32x4 accP[4][2] = {};
    f32x4 accG[4][2] = {};
    #pragma unroll
    for (int kk = 0; kk < 4; ++kk) {
        bf16x8 aP[4], aG[4], bz[2];
        #pragma unroll
        for (int m = 0; m < 4; ++m) {
            int rd = wd * 64 + m * 16 + lr;
            int phys = (kk * 4 + lh) ^ (rd & 7);
            aP[m] = *(const bf16x8*)((const char*)wP + rd * 256 + phys * 16);
            aG[m] = *(const bf16x8*)((const char*)wG + rd * 256 + phys * 16);
        }
        #pragma unroll
        for (int n = 0; n < 2; ++n) {
            int rz = wr2 * 32 + n * 16 + lr;
            int phys = (kk * 4 + lh) ^ (rz & 7);
            bz[n] = *(const bf16x8*)((const char*)zt + rz * 256 + phys * 16);
        }
        #pragma unroll
        for (int m = 0; m < 4; ++m)
            #pragma unroll
            for (int n = 0; n < 2; ++n) {
                accP[m][n] = __builtin_amdgcn_mfma_f32_16x16x32_bf16(aP[m], bz[n], accP[m][n], 0, 0, 0);
                accG[m][n] = __builtin_amdgcn_mfma_f32_16x16x32_bf16(aG[m], bz[n], accG[m][n], 0, 0, 0);
            }
    }

    #pragma unroll
    for (int m = 0; m < 4; ++m)
        #pragma unroll
        for (int reg = 0; reg < 4; ++reg) {
            int d = wd * 64 + m * 16 + lh * 4 + reg;
            float bp = bPsrc[d], bg = bGsrc[d];
            #pragma unroll
            for (int n = 0; n < 2; ++n) {
                int r = wr2 * 32 + n * 16 + lr;
                float g = accG[m][n][reg] + bg;
                float p = accP[m][n][reg] + bp;
                float val = p * (1.f / (1.f + __expf(-g)));
                dst[(size_t)d * NSQ + row0 + r] = (bf16)val;
            }
        }
}

// ---------------- K3: tri_t[d] = L_d (768x768) @ R_d^T, 128 batches ---------
__global__ __launch_bounds__(256, 2) void k_tri(
    const bf16* __restrict__ left_t, const bf16* __restrict__ right_t, bf16* __restrict__ tri_t)
{
    __shared__ bf16 at[2][128 * 32];
    __shared__ bf16 bt[2][128 * 32];
    const int t = threadIdx.x;
    const int d = blockIdx.y;
    const int ti = blockIdx.x / 6, tj = blockIdx.x % 6;
    const bf16* A = left_t + (size_t)d * NSQ;
    const bf16* B = right_t + (size_t)d * NSQ;
    const int i0 = ti * 128, j0 = tj * 128;

    auto stage = [&](int buf, int kt) {
        int k0 = kt * 32;
        #pragma unroll
        for (int c = 0; c < 2; ++c) {
            int s = c * 256 + t;           // 512 slots of 16B per tile
            int r = s >> 2, cp = s & 3, cl = cp ^ ((r >> 1) & 3);
            gld16(A + (size_t)(i0 + r) * 768 + k0 + cl * 8, (char*)at[buf] + s * 16);
            gld16(B + (size_t)(j0 + r) * 768 + k0 + cl * 8, (char*)bt[buf] + s * 16);
        }
    };

    const int lane = t & 63, wid = t >> 6;
    const int wr = wid >> 1, wc = wid & 1;
    const int lr = lane & 15, lh = lane >> 4;

    f32x4 acc[4][4] = {};

    stage(0, 0);
    __syncthreads();
    for (int kt = 0; kt < 24; ++kt) {
        if (kt < 23) stage((kt + 1) & 1, kt + 1);
        const bf16* ab = at[kt & 1];
        const bf16* bb = bt[kt & 1];
        bf16x8 af[4], bff[4];
        #pragma unroll
        for (int m = 0; m < 4; ++m) {
            int r = wr * 64 + m * 16 + lr;
            int phys = lh ^ ((r >> 1) & 3);
            af[m] = *(const bf16x8*)((const char*)ab + r * 64 + phys * 16);
        }
        #pragma unroll
        for (int n = 0; n < 4; ++n) {
            int r = wc * 64 + n * 16 + lr;
            int phys = lh ^ ((r >> 1) & 3);
            bff[n] = *(const bf16x8*)((const char*)bb + r * 64 + phys * 16);
        }
        #pragma unroll
        for (int m = 0; m < 4; ++m)
            #pragma unroll
            for (int n = 0; n < 4; ++n)
                acc[m][n] = __builtin_amdgcn_mfma_f32_16x16x32_bf16(af[m], bff[n], acc[m][n], 0, 0, 0);
        __syncthreads();
    }

    bf16* C = tri_t + (size_t)d * NSQ;
    #pragma unroll
    for (int m = 0; m < 4; ++m)
        #pragma unroll
        for (int n = 0; n < 4; ++n)
            #pragma unroll
            for (int reg = 0; reg < 4; ++reg) {
                int ri = i0 + wr * 64 + m * 16 + lh * 4 + reg;
                int cj = j0 + wc * 64 + n * 16 + lr;
                C[(size_t)ri * 768 + cj] = (bf16)acc[m][n][reg];
            }
}

// ---------------- K4: LN over d of tri_t[d][ij] -> tri_ln[ij][d] ------------
__global__ __launch_bounds__(256, 2) void k_cln(
    const bf16* __restrict__ tri_t, const float* __restrict__ cnw, const float* __restrict__ cnb,
    bf16* __restrict__ tri_ln)
{
    __shared__ bf16 tile[256 * 128];   // 64 KB
    const int t = threadIdx.x;
    const size_t ij = (size_t)blockIdx.x * 256 + t;
    float s1 = 0.f, s2 = 0.f;
    for (int dd = 0; dd < 128; ++dd) {
        float v = (float)tri_t[(size_t)dd * NSQ + ij];
        s1 += v; s2 += v * v;
    }
    float mean = s1 * (1.f / 128.f);
    float rstd = rsqrtf(s2 * (1.f / 128.f) - mean * mean + EPS);
    for (int dc = 0; dc < 16; ++dc) {
        bf16x8 pk;
        #pragma unroll
        for (int e = 0; e < 8; ++e) {
            int dd = dc * 8 + e;
            float v = (float)tri_t[(size_t)dd * NSQ + ij];
            pk[e] = (bf16)((v - mean) * rstd * cnw[dd] + cnb[dd]);
        }
        *(bf16x8*)((char*)tile + t * 256 + (dc ^ (t & 7)) * 16) = pk;
    }
    __syncthreads();
    const size_t ij0 = (size_t)blockIdx.x * 256;
    #pragma unroll
    for (int c = 0; c < 16; ++c) {
        int s = c * 256 + t;
        int rl = s >> 4, cp = s & 15, cl = cp ^ (rl & 7);
        *(bf16x8*)(tri_ln + (ij0 + rl) * 128 + cl * 8) =
            *(const bf16x8*)((const char*)tile + rl * 256 + cp * 16);
    }
}

// ---------------- K5: out = LN(pair + sigmoid(pair@og^T+bg) * (tri_ln@op^T+bo))
__global__ __launch_bounds__(512, 2) void k_final(
    const float* __restrict__ pair, const bf16* __restrict__ tri_ln,
    const bf16* __restrict__ wbf,
    const float* __restrict__ op_b, const float* __restrict__ og_b,
    const float* __restrict__ lnow, const float* __restrict__ lnob,
    float* __restrict__ out)
{
    __shared__ char smem[96 * 1024];
    bf16* pt  = (bf16*)smem;                    // [64][128] bf16, 16 KB
    bf16* tt  = (bf16*)(smem + 16 * 1024);      // [64][128] bf16, 16 KB
    bf16* wog = (bf16*)(smem + 32 * 1024);      // [128][128] bf16, 32 KB
    bf16* wop = (bf16*)(smem + 64 * 1024);      // [128][128] bf16, 32 KB
    float* ub = (float*)(smem + 32 * 1024);     // [64][132] fp32 (reuses weights)

    const int t = threadIdx.x;
    const int row0 = blockIdx.x * 64;

    // stage tri_ln tile
    #pragma unroll
    for (int c = 0; c < 2; ++c) {
        int s = c * 512 + t;
        int r = s >> 4, cp = s & 15, cl = cp ^ (r & 7);
        gld16(tri_ln + (size_t)(row0 + r) * 128 + cl * 8, (char*)tt + s * 16);
    }
    // stage weights
    const bf16* opsrc = wbf + 4 * 16384;
    const bf16* ogsrc = wbf + 5 * 16384;
    #pragma unroll
    for (int c = 0; c < 4; ++c) {
        int s = c * 512 + t;
        int r = s >> 4, cp = s & 15, cl = cp ^ (r & 7);
        gld16(ogsrc + r * 128 + cl * 8, (char*)wog + s * 16);
        gld16(opsrc + r * 128 + cl * 8, (char*)wop + s * 16);
    }
    // stage pair tile (fp32 -> bf16 reg staging)
    {
        int r = t >> 3, q = t & 7;
        const float* prow = pair + (size_t)(row0 + r) * 128 + q * 16;
        #pragma unroll
        for (int h = 0; h < 2; ++h) {
            f32x4 v0 = *(const f32x4*)(prow + h * 8);
            f32x4 v1 = *(const f32x4*)(prow + h * 8 + 4);
            bf16x8 pk;
            pk[0] = (bf16)v0[0]; pk[1] = (bf16)v0[1]; pk[2] = (bf16)v0[2]; pk[3] = (bf16)v0[3];
            pk[4] = (bf16)v1[0]; pk[5] = (bf16)v1[1]; pk[6] = (bf16)v1[2]; pk[7] = (bf16)v1[3];
            int cl = q * 2 + h;
            *(bf16x8*)((char*)pt + r * 256 + (cl ^ (r & 7)) * 16) = pk;
        }
    }
    __syncthreads();

    const int lane = t & 63, wid = t >> 6;
    const int wd = wid & 1, wr = wid >> 1;     // wd: d-half, wr: row-16 group
    const int lr = lane & 15, lh = lane >> 4;

    f32x4 accOG[4] = {};
    f32x4 accOP[4] = {};
    #pragma unroll
    for (int kk = 0; kk < 4; ++kk) {
        bf16x8 ag[4], ao[4], bp, btl;
        #pragma unroll
        for (int m = 0; m < 4; ++m) {
            int dd = wd * 64 + m * 16 + lr;
            int phys = (kk * 4 + lh) ^ (dd & 7);
            ag[m] = *(const bf16x8*)((const char*)wog + dd * 256 + phys * 16);
            ao[m] = *(const bf16x8*)((const char*)wop + dd * 256 + phys * 16);
        }
        {
            int rr = wr * 16 + lr;
            int phys = (kk * 4 + lh) ^ (rr & 7);
            bp  = *(const bf16x8*)((const char*)pt + rr * 256 + phys * 16);
            btl = *(const bf16x8*)((const char*)tt + rr * 256 + phys * 16);
        }
        #pragma unroll
        for (int m = 0; m < 4; ++m) {
            accOG[m] = __builtin_amdgcn_mfma_f32_16x16x32_bf16(ag[m], bp, accOG[m], 0, 0, 0);
            accOP[m] = __builtin_amdgcn_mfma_f32_16x16x32_bf16(ao[m], btl, accOP[m], 0, 0, 0);
        }
    }
    __syncthreads();   // all waves done reading weights before ub overwrite

    #pragma unroll
    for (int m = 0; m < 4; ++m)
        #pragma unroll
        for (int reg = 0; reg < 4; ++reg) {
            int dd = wd * 64 + m * 16 + lh * 4 + reg;
            float g = accOG[m][reg] + og_b[dd];
            float p = accOP[m][reg] + op_b[dd];
            int rr = wr * 16 + lr;
            ub[rr * 132 + dd] = p * (1.f / (1.f + __expf(-g)));
        }
    __syncthreads();

    // phase 2: residual + final LN, 8 threads/row
    {
        int r = t >> 3, q = t & 7;
        const float* prow = pair + (size_t)(row0 + r) * 128 + q * 16;
        float x[16];
        #pragma unroll
        for (int h = 0; h < 4; ++h) {
            f32x4 pv = *(const f32x4*)(prow + h * 4);
            f32x4 uv = *(const f32x4*)(ub + r * 132 + q * 16 + h * 4);
            x[h*4+0] = pv[0] + uv[0]; x[h*4+1] = pv[1] + uv[1];
            x[h*4+2] = pv[2] + uv[2]; x[h*4+3] = pv[3] + uv[3];
        }
        float s1 = 0.f, s2 = 0.f;
        #pragma unroll
        for (int j = 0; j < 16; ++j) { s1 += x[j]; s2 += x[j] * x[j]; }
        s1 += __shfl_xor(s1, 1); s2 += __shfl_xor(s2, 1);
        s1 += __shfl_xor(s1, 2); s2 += __shfl_xor(s2, 2);
        s1 += __shfl_xor(s1, 4); s2 += __shfl_xor(s2, 4);
        float mean = s1 * (1.f / 128.f);
        float rstd = rsqrtf(s2 * (1.f / 128.f) - mean * mean + EPS);
        float* orow = out + (size_t)(row0 + r) * 128 + q * 16;
        #pragma unroll
        for (int h = 0; h < 4; ++h) {
            f32x4 wv = *(const f32x4*)(lnow + q * 16 + h * 4);
            f32x4 bv = *(const f32x4*)(lnob + q * 16 + h * 4);
            f32x4 o;
            #pragma unroll
            for (int e = 0; e < 4; ++e)
                o[e] = (x[h * 4 + e] - mean) * rstd * wv[e] + bv[e];
            *(f32x4*)(orow + h * 4) = o;
        }
    }
}

extern "C" void kernel_launch(void* const* d_in, const int* in_sizes, int n_in,
                              void* d_out, int out_size, void* d_ws, size_t ws_size,
                              hipStream_t stream) {
    const float* pair    = (const float*)d_in[0];
    const float* ln_in_w = (const float*)d_in[1];
    const float* ln_in_b = (const float*)d_in[2];
    const float* lp_w    = (const float*)d_in[3];
    const float* lp_b    = (const float*)d_in[4];
    const float* lg_w    = (const float*)d_in[5];
    const float* lg_b    = (const float*)d_in[6];
    const float* rp_w    = (const float*)d_in[7];
    const float* rp_b    = (const float*)d_in[8];
    const float* rg_w    = (const float*)d_in[9];
    const float* rg_b    = (const float*)d_in[10];
    const float* cn_w    = (const float*)d_in[11];
    const float* cn_b    = (const float*)d_in[12];
    const float* op_w    = (const float*)d_in[13];
    const float* op_b    = (const float*)d_in[14];
    const float* og_w    = (const float*)d_in[15];
    const float* og_b    = (const float*)d_in[16];
    const float* ln_out_w = (const float*)d_in[17];
    const float* ln_out_b = (const float*)d_in[18];

    // Buffer plan (tight ws):
    //   d_out (302 MB fp32) doubles as scratch: left_t in lower half, tri_t upper.
    //   ws: wbf (192 KB) + right_t (151 MB); tri_ln reuses right_t slot after K3.
    const size_t HALF = (size_t)128 * NSQ * 2;   // 150,994,944 B
    char* ws = (char*)d_ws;
    bf16* wbf     = (bf16*)ws;
    bf16* right_t = (bf16*)(ws + 196608);
    bf16* tri_ln  = right_t;                      // reuse after K3
    bf16* left_t  = (bf16*)d_out;
    bf16* tri_t   = (bf16*)((char*)d_out + HALF);

    k_convert_w<<<dim3(64, 6), 256, 0, stream>>>(lp_w, lg_w, rp_w, rg_w, op_w, og_w, wbf);
    k_ln_gate<<<dim3(NSQ / 64, 2), 256, 0, stream>>>(pair, ln_in_w, ln_in_b, wbf,
                                                     lp_b, lg_b, rp_b, rg_b, left_t, right_t);
    k_tri<<<dim3(36, 128), 256, 0, stream>>>(left_t, right_t, tri_t);
    k_cln<<<dim3(NSQ / 256), 256, 0, stream>>>(tri_t, cn_w, cn_b, tri_ln);
    k_final<<<dim3(NSQ / 64), 512, 0, stream>>>(pair, tri_ln, wbf, op_b, og_b,
                                                ln_out_w, ln_out_b, (float*)d_out);
}

// Round 2
// 829.103 us; speedup vs baseline: 1.2276x; 1.2276x over previous
//
#include <hip/hip_runtime.h>

#define N 768
#define D 128
#define NSQ (N*N)
#define EPS 1e-5f

typedef __bf16 bf16;
typedef __bf16 bf16x8 __attribute__((ext_vector_type(8)));
typedef float f32x4 __attribute__((ext_vector_type(4)));

__device__ __forceinline__ void gld16(const void* g, void* l) {
    __builtin_amdgcn_global_load_lds(
        (const __attribute__((address_space(1))) unsigned int*)g,
        (__attribute__((address_space(3))) unsigned int*)l, 16, 0, 0);
}

// ---------------- K0: convert 6 weight matrices fp32 -> bf16 ----------------
__global__ void k_convert_w(const float* __restrict__ lp, const float* __restrict__ lg,
                            const float* __restrict__ rp, const float* __restrict__ rg,
                            const float* __restrict__ op, const float* __restrict__ og,
                            bf16* __restrict__ dst) {
    const float* srcs[6] = {lp, lg, rp, rg, op, og};
    int m = blockIdx.y;
    int i = blockIdx.x * 256 + threadIdx.x;   // 64 blocks x 256 = 16384
    dst[m * 16384 + i] = (bf16)srcs[m][i];
}

// ---------------- K1v2: fused LN + 4 GEMMs + gates, grid-stride -------------
// 512 threads = 8 waves; wave = (side, d-quarter). Weights live in REGISTERS
// (loaded once per block). LDS = double-buffered 64-row z tile only.
// Transposed store: {left_t|right_t}[d][row].
__global__ __launch_bounds__(512, 2) void k_ln_gate2(
    const float* __restrict__ pair, const float* __restrict__ lnw, const float* __restrict__ lnb,
    const bf16* __restrict__ wbf,
    const float* __restrict__ lp_b, const float* __restrict__ lg_b,
    const float* __restrict__ rp_b, const float* __restrict__ rg_b,
    bf16* __restrict__ left_t, bf16* __restrict__ right_t)
{
    __shared__ bf16 zt[2][64 * 128];   // 2 x 16 KB, xor-swizzled 16B chunks

    const int t = threadIdx.x;
    const int lane = t & 63, wid = t >> 6;
    const int side = wid >> 2, dq = wid & 3;      // wave's matrix side + d-quarter
    const int lr = lane & 15, lh = lane >> 4;

    const bf16* wPsrc = wbf + (side ? 2 : 0) * 16384;
    const bf16* wGsrc = wbf + (side ? 3 : 1) * 16384;
    const float* bPp = side ? rp_b : lp_b;
    const float* bGp = side ? rg_b : lg_b;
    bf16* dst = side ? right_t : left_t;

    // A-fragments (weights) held in registers for the whole kernel:
    // rows rd = dq*32 + m*16 + lr, k-slice (kk*4+lh)*8. 64 VGPRs total.
    bf16x8 aP[4][2], aG[4][2];
    #pragma unroll
    for (int kk = 0; kk < 4; ++kk)
        #pragma unroll
        for (int m = 0; m < 2; ++m) {
            int rd = dq * 32 + m * 16 + lr;
            aP[kk][m] = *(const bf16x8*)(wPsrc + rd * 128 + (kk * 4 + lh) * 8);
            aG[kk][m] = *(const bf16x8*)(wGsrc + rd * 128 + (kk * 4 + lh) * 8);
        }

    // LN lane geometry: 8 threads per row
    const int r8 = t >> 3, q = t & 7;

    // LN gamma/beta slice for this thread's 16 columns (hoisted)
    f32x4 lw0 = *(const f32x4*)(lnw + q * 16);
    f32x4 lw1 = *(const f32x4*)(lnw + q * 16 + 4);
    f32x4 lw2 = *(const f32x4*)(lnw + q * 16 + 8);
    f32x4 lw3 = *(const f32x4*)(lnw + q * 16 + 12);
    f32x4 lb0 = *(const f32x4*)(lnb + q * 16);
    f32x4 lb1 = *(const f32x4*)(lnb + q * 16 + 4);
    f32x4 lb2 = *(const f32x4*)(lnb + q * 16 + 8);
    f32x4 lb3 = *(const f32x4*)(lnb + q * 16 + 12);

    const int bid = blockIdx.x, gstride = gridDim.x;

    // prefetch first pair tile into registers
    f32x4 p0, p1, p2, p3;
    {
        const float* prow = pair + (size_t)(bid * 64 + r8) * 128 + q * 16;
        p0 = *(const f32x4*)(prow);
        p1 = *(const f32x4*)(prow + 4);
        p2 = *(const f32x4*)(prow + 8);
        p3 = *(const f32x4*)(prow + 12);
    }

    int buf = 0;
    for (int tile = bid; tile < NSQ / 64; tile += gstride) {
        const int row0 = tile * 64;

        // ---- layernorm of prefetched 16 elements, 8-lane reduction ----
        float x[16];
        #pragma unroll
        for (int e = 0; e < 4; ++e) {
            x[e] = p0[e]; x[4 + e] = p1[e]; x[8 + e] = p2[e]; x[12 + e] = p3[e];
        }
        float s1 = 0.f, s2 = 0.f;
        #pragma unroll
        for (int j = 0; j < 16; ++j) { s1 += x[j]; s2 += x[j] * x[j]; }
        s1 += __shfl_xor(s1, 1); s2 += __shfl_xor(s2, 1);
        s1 += __shfl_xor(s1, 2); s2 += __shfl_xor(s2, 2);
        s1 += __shfl_xor(s1, 4); s2 += __shfl_xor(s2, 4);
        float mean = s1 * (1.f / 128.f);
        float rstd = rsqrtf(s2 * (1.f / 128.f) - mean * mean + EPS);

        bf16x8 pk0, pk1;
        #pragma unroll
        for (int e = 0; e < 4; ++e) {
            pk0[e]     = (bf16)((x[e]      - mean) * rstd * lw0[e] + lb0[e]);
            pk0[4 + e] = (bf16)((x[4 + e]  - mean) * rstd * lw1[e] + lb1[e]);
            pk1[e]     = (bf16)((x[8 + e]  - mean) * rstd * lw2[e] + lb2[e]);
            pk1[4 + e] = (bf16)((x[12 + e] - mean) * rstd * lw3[e] + lb3[e]);
        }
        {
            char* zb = (char*)&zt[buf][0];
            *(bf16x8*)(zb + r8 * 256 + ((q * 2)     ^ (r8 & 7)) * 16) = pk0;
            *(bf16x8*)(zb + r8 * 256 + ((q * 2 + 1) ^ (r8 & 7)) * 16) = pk1;
        }
        __syncthreads();

        // ---- prefetch next tile (latency hidden under MFMA) ----
        int nt = tile + gstride;
        if (nt < NSQ / 64) {
            const float* prow = pair + (size_t)(nt * 64 + r8) * 128 + q * 16;
            p0 = *(const f32x4*)(prow);
            p1 = *(const f32x4*)(prow + 4);
            p2 = *(const f32x4*)(prow + 8);
            p3 = *(const f32x4*)(prow + 12);
        }

        // ---- dual GEMM from registers x LDS ----
        f32x4 accP[2][4] = {};
        f32x4 accG[2][4] = {};
        const char* zb = (const char*)&zt[buf][0];
        #pragma unroll
        for (int kk = 0; kk < 4; ++kk) {
            bf16x8 bz[4];
            #pragma unroll
            for (int n = 0; n < 4; ++n) {
                int rz = n * 16 + lr;
                bz[n] = *(const bf16x8*)(zb + rz * 256 + (((kk * 4 + lh)) ^ (rz & 7)) * 16);
            }
            #pragma unroll
            for (int m = 0; m < 2; ++m)
                #pragma unroll
                for (int n = 0; n < 4; ++n) {
                    accP[m][n] = __builtin_amdgcn_mfma_f32_16x16x32_bf16(aP[kk][m], bz[n], accP[m][n], 0, 0, 0);
                    accG[m][n] = __builtin_amdgcn_mfma_f32_16x16x32_bf16(aG[kk][m], bz[n], accG[m][n], 0, 0, 0);
                }
        }

        // ---- gate + transposed store ----
        #pragma unroll
        for (int m = 0; m < 2; ++m) {
            f32x4 vbP = *(const f32x4*)(bPp + dq * 32 + m * 16 + lh * 4);
            f32x4 vbG = *(const f32x4*)(bGp + dq * 32 + m * 16 + lh * 4);
            #pragma unroll
            for (int reg = 0; reg < 4; ++reg) {
                int d = dq * 32 + m * 16 + lh * 4 + reg;
                #pragma unroll
                for (int n = 0; n < 4; ++n) {
                    float g = accG[m][n][reg] + vbG[reg];
                    float p = accP[m][n][reg] + vbP[reg];
                    float val = p * (1.f / (1.f + __expf(-g)));
                    dst[(size_t)d * NSQ + row0 + n * 16 + lr] = (bf16)val;
                }
            }
        }
        buf ^= 1;
        __syncthreads();
    }
}

// ---------------- K3: tri_t[d] = L_d (768x768) @ R_d^T, 128 batches ---------
__global__ __launch_bounds__(256, 2) void k_tri(
    const bf16* __restrict__ left_t, const bf16* __restrict__ right_t, bf16* __restrict__ tri_t)
{
    __shared__ bf16 at[2][128 * 32];
    __shared__ bf16 bt[2][128 * 32];
    const int t = threadIdx.x;
    const int d = blockIdx.y;
    const int ti = blockIdx.x / 6, tj = blockIdx.x % 6;
    const bf16* A = left_t + (size_t)d * NSQ;
    const bf16* B = right_t + (size_t)d * NSQ;
    const int i0 = ti * 128, j0 = tj * 128;

    auto stage = [&](int buf, int kt) {
        int k0 = kt * 32;
        #pragma unroll
        for (int c = 0; c < 2; ++c) {
            int s = c * 256 + t;           // 512 slots of 16B per tile
            int r = s >> 2, cp = s & 3, cl = cp ^ ((r >> 1) & 3);
            gld16(A + (size_t)(i0 + r) * 768 + k0 + cl * 8, (char*)at[buf] + s * 16);
            gld16(B + (size_t)(j0 + r) * 768 + k0 + cl * 8, (char*)bt[buf] + s * 16);
        }
    };

    const int lane = t & 63, wid = t >> 6;
    const int wr = wid >> 1, wc = wid & 1;
    const int lr = lane & 15, lh = lane >> 4;

    f32x4 acc[4][4] = {};

    stage(0, 0);
    __syncthreads();
    for (int kt = 0; kt < 24; ++kt) {
        if (kt < 23) stage((kt + 1) & 1, kt + 1);
        const bf16* ab = at[kt & 1];
        const bf16* bb = bt[kt & 1];
        bf16x8 af[4], bff[4];
        #pragma unroll
        for (int m = 0; m < 4; ++m) {
            int r = wr * 64 + m * 16 + lr;
            int phys = lh ^ ((r >> 1) & 3);
            af[m] = *(const bf16x8*)((const char*)ab + r * 64 + phys * 16);
        }
        #pragma unroll
        for (int n = 0; n < 4; ++n) {
            int r = wc * 64 + n * 16 + lr;
            int phys = lh ^ ((r >> 1) & 3);
            bff[n] = *(const bf16x8*)((const char*)bb + r * 64 + phys * 16);
        }
        #pragma unroll
        for (int m = 0; m < 4; ++m)
            #pragma unroll
            for (int n = 0; n < 4; ++n)
                acc[m][n] = __builtin_amdgcn_mfma_f32_16x16x32_bf16(af[m], bff[n], acc[m][n], 0, 0, 0);
        __syncthreads();
    }

    bf16* C = tri_t + (size_t)d * NSQ;
    #pragma unroll
    for (int m = 0; m < 4; ++m)
        #pragma unroll
        for (int n = 0; n < 4; ++n)
            #pragma unroll
            for (int reg = 0; reg < 4; ++reg) {
                int ri = i0 + wr * 64 + m * 16 + lh * 4 + reg;
                int cj = j0 + wc * 64 + n * 16 + lr;
                C[(size_t)ri * 768 + cj] = (bf16)acc[m][n][reg];
            }
}

// ---------------- K4: LN over d of tri_t[d][ij] -> tri_ln[ij][d] ------------
__global__ __launch_bounds__(256, 2) void k_cln(
    const bf16* __restrict__ tri_t, const float* __restrict__ cnw, const float* __restrict__ cnb,
    bf16* __restrict__ tri_ln)
{
    __shared__ bf16 tile[256 * 128];   // 64 KB
    const int t = threadIdx.x;
    const size_t ij = (size_t)blockIdx.x * 256 + t;
    float s1 = 0.f, s2 = 0.f;
    for (int dd = 0; dd < 128; ++dd) {
        float v = (float)tri_t[(size_t)dd * NSQ + ij];
        s1 += v; s2 += v * v;
    }
    float mean = s1 * (1.f / 128.f);
    float rstd = rsqrtf(s2 * (1.f / 128.f) - mean * mean + EPS);
    for (int dc = 0; dc < 16; ++dc) {
        bf16x8 pk;
        #pragma unroll
        for (int e = 0; e < 8; ++e) {
            int dd = dc * 8 + e;
            float v = (float)tri_t[(size_t)dd * NSQ + ij];
            pk[e] = (bf16)((v - mean) * rstd * cnw[dd] + cnb[dd]);
        }
        *(bf16x8*)((char*)tile + t * 256 + (dc ^ (t & 7)) * 16) = pk;
    }
    __syncthreads();
    const size_t ij0 = (size_t)blockIdx.x * 256;
    #pragma unroll
    for (int c = 0; c < 16; ++c) {
        int s = c * 256 + t;
        int rl = s >> 4, cp = s & 15, cl = cp ^ (rl & 7);
        *(bf16x8*)(tri_ln + (ij0 + rl) * 128 + cl * 8) =
            *(const bf16x8*)((const char*)tile + rl * 256 + cp * 16);
    }
}

// ---------------- K5: out = LN(pair + sigmoid(pair@og^T+bg) * (tri_ln@op^T+bo))
__global__ __launch_bounds__(512, 2) void k_final(
    const float* __restrict__ pair, const bf16* __restrict__ tri_ln,
    const bf16* __restrict__ wbf,
    const float* __restrict__ op_b, const float* __restrict__ og_b,
    const float* __restrict__ lnow, const float* __restrict__ lnob,
    float* __restrict__ out)
{
    __shared__ char smem[96 * 1024];
    bf16* pt  = (bf16*)smem;                    // [64][128] bf16, 16 KB
    bf16* tt  = (bf16*)(smem + 16 * 1024);      // [64][128] bf16, 16 KB
    bf16* wog = (bf16*)(smem + 32 * 1024);      // [128][128] bf16, 32 KB
    bf16* wop = (bf16*)(smem + 64 * 1024);      // [128][128] bf16, 32 KB
    float* ub = (float*)(smem + 32 * 1024);     // [64][132] fp32 (reuses weights)

    const int t = threadIdx.x;
    const int row0 = blockIdx.x * 64;

    // stage tri_ln tile
    #pragma unroll
    for (int c = 0; c < 2; ++c) {
        int s = c * 512 + t;
        int r = s >> 4, cp = s & 15, cl = cp ^ (r & 7);
        gld16(tri_ln + (size_t)(row0 + r) * 128 + cl * 8, (char*)tt + s * 16);
    }
    // stage weights
    const bf16* opsrc = wbf + 4 * 16384;
    const bf16* ogsrc = wbf + 5 * 16384;
    #pragma unroll
    for (int c = 0; c < 4; ++c) {
        int s = c * 512 + t;
        int r = s >> 4, cp = s & 15, cl = cp ^ (r & 7);
        gld16(ogsrc + r * 128 + cl * 8, (char*)wog + s * 16);
        gld16(opsrc + r * 128 + cl * 8, (char*)wop + s * 16);
    }
    // stage pair tile (fp32 -> bf16 reg staging)
    {
        int r = t >> 3, q = t & 7;
        const float* prow = pair + (size_t)(row0 + r) * 128 + q * 16;
        #pragma unroll
        for (int h = 0; h < 2; ++h) {
            f32x4 v0 = *(const f32x4*)(prow + h * 8);
            f32x4 v1 = *(const f32x4*)(prow + h * 8 + 4);
            bf16x8 pk;
            pk[0] = (bf16)v0[0]; pk[1] = (bf16)v0[1]; pk[2] = (bf16)v0[2]; pk[3] = (bf16)v0[3];
            pk[4] = (bf16)v1[0]; pk[5] = (bf16)v1[1]; pk[6] = (bf16)v1[2]; pk[7] = (bf16)v1[3];
            int cl = q * 2 + h;
            *(bf16x8*)((char*)pt + r * 256 + (cl ^ (r & 7)) * 16) = pk;
        }
    }
    __syncthreads();

    const int lane = t & 63, wid = t >> 6;
    const int wd = wid & 1, wr = wid >> 1;     // wd: d-half, wr: row-16 group
    const int lr = lane & 15, lh = lane >> 4;

    f32x4 accOG[4] = {};
    f32x4 accOP[4] = {};
    #pragma unroll
    for (int kk = 0; kk < 4; ++kk) {
        bf16x8 ag[4], ao[4], bp, btl;
        #pragma unroll
        for (int m = 0; m < 4; ++m) {
            int dd = wd * 64 + m * 16 + lr;
            int phys = (kk * 4 + lh) ^ (dd & 7);
            ag[m] = *(const bf16x8*)((const char*)wog + dd * 256 + phys * 16);
            ao[m] = *(const bf16x8*)((const char*)wop + dd * 256 + phys * 16);
        }
        {
            int rr = wr * 16 + lr;
            int phys = (kk * 4 + lh) ^ (rr & 7);
            bp  = *(const bf16x8*)((const char*)pt + rr * 256 + phys * 16);
            btl = *(const bf16x8*)((const char*)tt + rr * 256 + phys * 16);
        }
        #pragma unroll
        for (int m = 0; m < 4; ++m) {
            accOG[m] = __builtin_amdgcn_mfma_f32_16x16x32_bf16(ag[m], bp, accOG[m], 0, 0, 0);
            accOP[m] = __builtin_amdgcn_mfma_f32_16x16x32_bf16(ao[m], btl, accOP[m], 0, 0, 0);
        }
    }
    __syncthreads();   // all waves done reading weights before ub overwrite

    #pragma unroll
    for (int m = 0; m < 4; ++m)
        #pragma unroll
        for (int reg = 0; reg < 4; ++reg) {
            int dd = wd * 64 + m * 16 + lh * 4 + reg;
            float g = accOG[m][reg] + og_b[dd];
            float p = accOP[m][reg] + op_b[dd];
            int rr = wr * 16 + lr;
            ub[rr * 132 + dd] = p * (1.f / (1.f + __expf(-g)));
        }
    __syncthreads();

    // phase 2: residual + final LN, 8 threads/row
    {
        int r = t >> 3, q = t & 7;
        const float* prow = pair + (size_t)(row0 + r) * 128 + q * 16;
        float x[16];
        #pragma unroll
        for (int h = 0; h < 4; ++h) {
            f32x4 pv = *(const f32x4*)(prow + h * 4);
            f32x4 uv = *(const f32x4*)(ub + r * 132 + q * 16 + h * 4);
            x[h*4+0] = pv[0] + uv[0]; x[h*4+1] = pv[1] + uv[1];
            x[h*4+2] = pv[2] + uv[2]; x[h*4+3] = pv[3] + uv[3];
        }
        float s1 = 0.f, s2 = 0.f;
        #pragma unroll
        for (int j = 0; j < 16; ++j) { s1 += x[j]; s2 += x[j] * x[j]; }
        s1 += __shfl_xor(s1, 1); s2 += __shfl_xor(s2, 1);
        s1 += __shfl_xor(s1, 2); s2 += __shfl_xor(s2, 2);
        s1 += __shfl_xor(s1, 4); s2 += __shfl_xor(s2, 4);
        float mean = s1 * (1.f / 128.f);
        float rstd = rsqrtf(s2 * (1.f / 128.f) - mean * mean + EPS);
        float* orow = out + (size_t)(row0 + r) * 128 + q * 16;
        #pragma unroll
        for (int h = 0; h < 4; ++h) {
            f32x4 wv = *(const f32x4*)(lnow + q * 16 + h * 4);
            f32x4 bv = *(const f32x4*)(lnob + q * 16 + h * 4);
            f32x4 o;
            #pragma unroll
            for (int e = 0; e < 4; ++e)
                o[e] = (x[h * 4 + e] - mean) * rstd * wv[e] + bv[e];
            *(f32x4*)(orow + h * 4) = o;
        }
    }
}

extern "C" void kernel_launch(void* const* d_in, const int* in_sizes, int n_in,
                              void* d_out, int out_size, void* d_ws, size_t ws_size,
                              hipStream_t stream) {
    const float* pair    = (const float*)d_in[0];
    const float* ln_in_w = (const float*)d_in[1];
    const float* ln_in_b = (const float*)d_in[2];
    const float* lp_w    = (const float*)d_in[3];
    const float* lp_b    = (const float*)d_in[4];
    const float* lg_w    = (const float*)d_in[5];
    const float* lg_b    = (const float*)d_in[6];
    const float* rp_w    = (const float*)d_in[7];
    const float* rp_b    = (const float*)d_in[8];
    const float* rg_w    = (const float*)d_in[9];
    const float* rg_b    = (const float*)d_in[10];
    const float* cn_w    = (const float*)d_in[11];
    const float* cn_b    = (const float*)d_in[12];
    const float* op_w    = (const float*)d_in[13];
    const float* op_b    = (const float*)d_in[14];
    const float* og_w    = (const float*)d_in[15];
    const float* og_b    = (const float*)d_in[16];
    const float* ln_out_w = (const float*)d_in[17];
    const float* ln_out_b = (const float*)d_in[18];

    const size_t HALF = (size_t)128 * NSQ * 2;   // 150,994,944 B
    char* ws = (char*)d_ws;
    bf16* wbf     = (bf16*)ws;
    bf16* right_t = (bf16*)(ws + 196608);
    bf16* tri_ln  = right_t;                      // reuse after K3
    bf16* left_t  = (bf16*)d_out;
    bf16* tri_t   = (bf16*)((char*)d_out + HALF);

    k_convert_w<<<dim3(64, 6), 256, 0, stream>>>(lp_w, lg_w, rp_w, rg_w, op_w, og_w, wbf);
    k_ln_gate2<<<dim3(512), 512, 0, stream>>>(pair, ln_in_w, ln_in_b, wbf,
                                              lp_b, lg_b, rp_b, rg_b, left_t, right_t);
    k_tri<<<dim3(36, 128), 256, 0, stream>>>(left_t, right_t, tri_t);
    k_cln<<<dim3(NSQ / 256), 256, 0, stream>>>(tri_t, cn_w, cn_b, tri_ln);
    k_final<<<dim3(NSQ / 64), 512, 0, stream>>>(pair, tri_ln, wbf, op_b, og_b,
                                                ln_out_w, ln_out_b, (float*)d_out);
}

// Round 3
// 687.938 us; speedup vs baseline: 1.4795x; 1.2052x over previous
//
#include <hip/hip_runtime.h>

#define N 768
#define D 128
#define NSQ (N*N)
#define EPS 1e-5f

typedef __bf16 bf16;
typedef __bf16 bf16x8 __attribute__((ext_vector_type(8)));
typedef float f32x4 __attribute__((ext_vector_type(4)));

__device__ __forceinline__ void gld16(const void* g, void* l) {
    __builtin_amdgcn_global_load_lds(
        (const __attribute__((address_space(1))) unsigned int*)g,
        (__attribute__((address_space(3))) unsigned int*)l, 16, 0, 0);
}

// ---------------- K0: convert 6 weight matrices fp32 -> bf16 ----------------
__global__ void k_convert_w(const float* __restrict__ lp, const float* __restrict__ lg,
                            const float* __restrict__ rp, const float* __restrict__ rg,
                            const float* __restrict__ op, const float* __restrict__ og,
                            bf16* __restrict__ dst) {
    const float* srcs[6] = {lp, lg, rp, rg, op, og};
    int m = blockIdx.y;
    int i = blockIdx.x * 256 + threadIdx.x;   // 64 blocks x 256 = 16384
    dst[m * 16384 + i] = (bf16)srcs[m][i];
}

// ---------------- K1v2: fused LN + 4 GEMMs + gates, grid-stride -------------
__global__ __launch_bounds__(512, 2) void k_ln_gate2(
    const float* __restrict__ pair, const float* __restrict__ lnw, const float* __restrict__ lnb,
    const bf16* __restrict__ wbf,
    const float* __restrict__ lp_b, const float* __restrict__ lg_b,
    const float* __restrict__ rp_b, const float* __restrict__ rg_b,
    bf16* __restrict__ left_t, bf16* __restrict__ right_t)
{
    __shared__ bf16 zt[2][64 * 128];   // 2 x 16 KB, xor-swizzled 16B chunks

    const int t = threadIdx.x;
    const int lane = t & 63, wid = t >> 6;
    const int side = wid >> 2, dq = wid & 3;      // wave's matrix side + d-quarter
    const int lr = lane & 15, lh = lane >> 4;

    const bf16* wPsrc = wbf + (side ? 2 : 0) * 16384;
    const bf16* wGsrc = wbf + (side ? 3 : 1) * 16384;
    const float* bPp = side ? rp_b : lp_b;
    const float* bGp = side ? rg_b : lg_b;
    bf16* dst = side ? right_t : left_t;

    // A-fragments (weights) held in registers for the whole kernel
    bf16x8 aP[4][2], aG[4][2];
    #pragma unroll
    for (int kk = 0; kk < 4; ++kk)
        #pragma unroll
        for (int m = 0; m < 2; ++m) {
            int rd = dq * 32 + m * 16 + lr;
            aP[kk][m] = *(const bf16x8*)(wPsrc + rd * 128 + (kk * 4 + lh) * 8);
            aG[kk][m] = *(const bf16x8*)(wGsrc + rd * 128 + (kk * 4 + lh) * 8);
        }

    const int r8 = t >> 3, q = t & 7;

    f32x4 lw0 = *(const f32x4*)(lnw + q * 16);
    f32x4 lw1 = *(const f32x4*)(lnw + q * 16 + 4);
    f32x4 lw2 = *(const f32x4*)(lnw + q * 16 + 8);
    f32x4 lw3 = *(const f32x4*)(lnw + q * 16 + 12);
    f32x4 lb0 = *(const f32x4*)(lnb + q * 16);
    f32x4 lb1 = *(const f32x4*)(lnb + q * 16 + 4);
    f32x4 lb2 = *(const f32x4*)(lnb + q * 16 + 8);
    f32x4 lb3 = *(const f32x4*)(lnb + q * 16 + 12);

    const int bid = blockIdx.x, gstride = gridDim.x;

    f32x4 p0, p1, p2, p3;
    {
        const float* prow = pair + (size_t)(bid * 64 + r8) * 128 + q * 16;
        p0 = *(const f32x4*)(prow);
        p1 = *(const f32x4*)(prow + 4);
        p2 = *(const f32x4*)(prow + 8);
        p3 = *(const f32x4*)(prow + 12);
    }

    int buf = 0;
    for (int tile = bid; tile < NSQ / 64; tile += gstride) {
        const int row0 = tile * 64;

        float x[16];
        #pragma unroll
        for (int e = 0; e < 4; ++e) {
            x[e] = p0[e]; x[4 + e] = p1[e]; x[8 + e] = p2[e]; x[12 + e] = p3[e];
        }
        float s1 = 0.f, s2 = 0.f;
        #pragma unroll
        for (int j = 0; j < 16; ++j) { s1 += x[j]; s2 += x[j] * x[j]; }
        s1 += __shfl_xor(s1, 1); s2 += __shfl_xor(s2, 1);
        s1 += __shfl_xor(s1, 2); s2 += __shfl_xor(s2, 2);
        s1 += __shfl_xor(s1, 4); s2 += __shfl_xor(s2, 4);
        float mean = s1 * (1.f / 128.f);
        float rstd = rsqrtf(s2 * (1.f / 128.f) - mean * mean + EPS);

        bf16x8 pk0, pk1;
        #pragma unroll
        for (int e = 0; e < 4; ++e) {
            pk0[e]     = (bf16)((x[e]      - mean) * rstd * lw0[e] + lb0[e]);
            pk0[4 + e] = (bf16)((x[4 + e]  - mean) * rstd * lw1[e] + lb1[e]);
            pk1[e]     = (bf16)((x[8 + e]  - mean) * rstd * lw2[e] + lb2[e]);
            pk1[4 + e] = (bf16)((x[12 + e] - mean) * rstd * lw3[e] + lb3[e]);
        }
        {
            char* zb = (char*)&zt[buf][0];
            *(bf16x8*)(zb + r8 * 256 + ((q * 2)     ^ (r8 & 7)) * 16) = pk0;
            *(bf16x8*)(zb + r8 * 256 + ((q * 2 + 1) ^ (r8 & 7)) * 16) = pk1;
        }
        __syncthreads();

        int nt = tile + gstride;
        if (nt < NSQ / 64) {
            const float* prow = pair + (size_t)(nt * 64 + r8) * 128 + q * 16;
            p0 = *(const f32x4*)(prow);
            p1 = *(const f32x4*)(prow + 4);
            p2 = *(const f32x4*)(prow + 8);
            p3 = *(const f32x4*)(prow + 12);
        }

        f32x4 accP[2][4] = {};
        f32x4 accG[2][4] = {};
        const char* zb = (const char*)&zt[buf][0];
        #pragma unroll
        for (int kk = 0; kk < 4; ++kk) {
            bf16x8 bz[4];
            #pragma unroll
            for (int n = 0; n < 4; ++n) {
                int rz = n * 16 + lr;
                bz[n] = *(const bf16x8*)(zb + rz * 256 + (((kk * 4 + lh)) ^ (rz & 7)) * 16);
            }
            #pragma unroll
            for (int m = 0; m < 2; ++m)
                #pragma unroll
                for (int n = 0; n < 4; ++n) {
                    accP[m][n] = __builtin_amdgcn_mfma_f32_16x16x32_bf16(aP[kk][m], bz[n], accP[m][n], 0, 0, 0);
                    accG[m][n] = __builtin_amdgcn_mfma_f32_16x16x32_bf16(aG[kk][m], bz[n], accG[m][n], 0, 0, 0);
                }
        }

        #pragma unroll
        for (int m = 0; m < 2; ++m) {
            f32x4 vbP = *(const f32x4*)(bPp + dq * 32 + m * 16 + lh * 4);
            f32x4 vbG = *(const f32x4*)(bGp + dq * 32 + m * 16 + lh * 4);
            #pragma unroll
            for (int reg = 0; reg < 4; ++reg) {
                int d = dq * 32 + m * 16 + lh * 4 + reg;
                #pragma unroll
                for (int n = 0; n < 4; ++n) {
                    float g = accG[m][n][reg] + vbG[reg];
                    float p = accP[m][n][reg] + vbP[reg];
                    float val = p * (1.f / (1.f + __expf(-g)));
                    dst[(size_t)d * NSQ + row0 + n * 16 + lr] = (bf16)val;
                }
            }
        }
        buf ^= 1;
        __syncthreads();
    }
}

// ---------------- K3v2: tri_t[d] = L_d @ R_d^T, XCD-pinned batch ------------
// Flat grid 4608 = 8 XCD x 16 d x 36 tiles. b&7 = XCD (dispatch round-robin),
// so all 36 tiles of a d run on ONE XCD -> panels L2-resident, fetched once.
__global__ __launch_bounds__(256, 4) void k_tri(
    const bf16* __restrict__ left_t, const bf16* __restrict__ right_t, bf16* __restrict__ tri_t)
{
    __shared__ bf16 at[2][128 * 32];
    __shared__ bf16 bt[2][128 * 32];
    const int t = threadIdx.x;
    const int b = blockIdx.x;
    const int xcd = b & 7;
    const int s = b >> 3;
    const int d = xcd * 16 + s / 36;
    const int tile = s % 36;
    const int ti = tile / 6, tj = tile % 6;   // tj fastest: consecutive blocks share A panel
    const bf16* A = left_t + (size_t)d * NSQ;
    const bf16* B = right_t + (size_t)d * NSQ;
    const int i0 = ti * 128, j0 = tj * 128;

    auto stage = [&](int buf, int kt) {
        int k0 = kt * 32;
        #pragma unroll
        for (int c = 0; c < 2; ++c) {
            int sl = c * 256 + t;           // 512 slots of 16B per tile
            int r = sl >> 2, cp = sl & 3, cl = cp ^ ((r >> 1) & 3);
            gld16(A + (size_t)(i0 + r) * 768 + k0 + cl * 8, (char*)at[buf] + sl * 16);
            gld16(B + (size_t)(j0 + r) * 768 + k0 + cl * 8, (char*)bt[buf] + sl * 16);
        }
    };

    const int lane = t & 63, wid = t >> 6;
    const int wr = wid >> 1, wc = wid & 1;
    const int lr = lane & 15, lh = lane >> 4;

    f32x4 acc[4][4] = {};

    stage(0, 0);
    __syncthreads();
    for (int kt = 0; kt < 24; ++kt) {
        if (kt < 23) stage((kt + 1) & 1, kt + 1);
        const bf16* ab = at[kt & 1];
        const bf16* bb = bt[kt & 1];
        bf16x8 af[4], bff[4];
        #pragma unroll
        for (int m = 0; m < 4; ++m) {
            int r = wr * 64 + m * 16 + lr;
            int phys = lh ^ ((r >> 1) & 3);
            af[m] = *(const bf16x8*)((const char*)ab + r * 64 + phys * 16);
        }
        #pragma unroll
        for (int n = 0; n < 4; ++n) {
            int r = wc * 64 + n * 16 + lr;
            int phys = lh ^ ((r >> 1) & 3);
            bff[n] = *(const bf16x8*)((const char*)bb + r * 64 + phys * 16);
        }
        #pragma unroll
        for (int m = 0; m < 4; ++m)
            #pragma unroll
            for (int n = 0; n < 4; ++n)
                acc[m][n] = __builtin_amdgcn_mfma_f32_16x16x32_bf16(af[m], bff[n], acc[m][n], 0, 0, 0);
        __syncthreads();
    }

    bf16* C = tri_t + (size_t)d * NSQ;
    #pragma unroll
    for (int m = 0; m < 4; ++m)
        #pragma unroll
        for (int n = 0; n < 4; ++n)
            #pragma unroll
            for (int reg = 0; reg < 4; ++reg) {
                int ri = i0 + wr * 64 + m * 16 + lh * 4 + reg;
                int cj = j0 + wc * 64 + n * 16 + lr;
                C[(size_t)ri * 768 + cj] = (bf16)acc[m][n][reg];
            }
}

// ---------------- K4v2: LN over d, single global read -----------------------
// Pass1: read tri_t once, stats + raw bf16 -> LDS (swizzled). Pass2: normalize
// during LDS->global transpose using per-row mean/rstd from LDS.
__global__ __launch_bounds__(256, 2) void k_cln(
    const bf16* __restrict__ tri_t, const float* __restrict__ cnw, const float* __restrict__ cnb,
    bf16* __restrict__ tri_ln)
{
    __shared__ bf16 tile[256 * 128];   // 64 KB raw values
    __shared__ float mrs[256][2];      // mean, rstd
    const int t = threadIdx.x;
    const size_t ij = (size_t)blockIdx.x * 256 + t;
    float s1 = 0.f, s2 = 0.f;
    for (int dc = 0; dc < 16; ++dc) {
        bf16x8 pk;
        #pragma unroll
        for (int e = 0; e < 8; ++e) {
            int dd = dc * 8 + e;
            bf16 raw = tri_t[(size_t)dd * NSQ + ij];
            float v = (float)raw;
            s1 += v; s2 += v * v;
            pk[e] = raw;
        }
        *(bf16x8*)((char*)tile + t * 256 + (dc ^ (t & 7)) * 16) = pk;
    }
    float mean = s1 * (1.f / 128.f);
    float rstd = rsqrtf(s2 * (1.f / 128.f) - mean * mean + EPS);
    mrs[t][0] = mean; mrs[t][1] = rstd;
    __syncthreads();
    const size_t ij0 = (size_t)blockIdx.x * 256;
    #pragma unroll
    for (int c = 0; c < 16; ++c) {
        int sl = c * 256 + t;
        int rl = sl >> 4, cp = sl & 15, cl = cp ^ (rl & 7);
        bf16x8 raw = *(const bf16x8*)((const char*)tile + rl * 256 + cp * 16);
        float m = mrs[rl][0], r = mrs[rl][1];
        f32x4 w0 = *(const f32x4*)(cnw + cl * 8);
        f32x4 w1 = *(const f32x4*)(cnw + cl * 8 + 4);
        f32x4 b0 = *(const f32x4*)(cnb + cl * 8);
        f32x4 b1 = *(const f32x4*)(cnb + cl * 8 + 4);
        bf16x8 o;
        #pragma unroll
        for (int e = 0; e < 4; ++e) {
            o[e]     = (bf16)(((float)raw[e]     - m) * r * w0[e] + b0[e]);
            o[4 + e] = (bf16)(((float)raw[4 + e] - m) * r * w1[e] + b1[e]);
        }
        *(bf16x8*)(tri_ln + (ij0 + rl) * 128 + cl * 8) = o;
    }
}

// ---------------- K5: out = LN(pair + sigmoid(pair@og^T+bg) * (tri_ln@op^T+bo))
__global__ __launch_bounds__(512, 2) void k_final(
    const float* __restrict__ pair, const bf16* __restrict__ tri_ln,
    const bf16* __restrict__ wbf,
    const float* __restrict__ op_b, const float* __restrict__ og_b,
    const float* __restrict__ lnow, const float* __restrict__ lnob,
    float* __restrict__ out)
{
    __shared__ char smem[96 * 1024];
    bf16* pt  = (bf16*)smem;                    // [64][128] bf16, 16 KB
    bf16* tt  = (bf16*)(smem + 16 * 1024);      // [64][128] bf16, 16 KB
    bf16* wog = (bf16*)(smem + 32 * 1024);      // [128][128] bf16, 32 KB
    bf16* wop = (bf16*)(smem + 64 * 1024);      // [128][128] bf16, 32 KB
    float* ub = (float*)(smem + 32 * 1024);     // [64][132] fp32 (reuses weights)

    const int t = threadIdx.x;
    const int row0 = blockIdx.x * 64;

    #pragma unroll
    for (int c = 0; c < 2; ++c) {
        int s = c * 512 + t;
        int r = s >> 4, cp = s & 15, cl = cp ^ (r & 7);
        gld16(tri_ln + (size_t)(row0 + r) * 128 + cl * 8, (char*)tt + s * 16);
    }
    const bf16* opsrc = wbf + 4 * 16384;
    const bf16* ogsrc = wbf + 5 * 16384;
    #pragma unroll
    for (int c = 0; c < 4; ++c) {
        int s = c * 512 + t;
        int r = s >> 4, cp = s & 15, cl = cp ^ (r & 7);
        gld16(ogsrc + r * 128 + cl * 8, (char*)wog + s * 16);
        gld16(opsrc + r * 128 + cl * 8, (char*)wop + s * 16);
    }
    {
        int r = t >> 3, q = t & 7;
        const float* prow = pair + (size_t)(row0 + r) * 128 + q * 16;
        #pragma unroll
        for (int h = 0; h < 2; ++h) {
            f32x4 v0 = *(const f32x4*)(prow + h * 8);
            f32x4 v1 = *(const f32x4*)(prow + h * 8 + 4);
            bf16x8 pk;
            pk[0] = (bf16)v0[0]; pk[1] = (bf16)v0[1]; pk[2] = (bf16)v0[2]; pk[3] = (bf16)v0[3];
            pk[4] = (bf16)v1[0]; pk[5] = (bf16)v1[1]; pk[6] = (bf16)v1[2]; pk[7] = (bf16)v1[3];
            int cl = q * 2 + h;
            *(bf16x8*)((char*)pt + r * 256 + (cl ^ (r & 7)) * 16) = pk;
        }
    }
    __syncthreads();

    const int lane = t & 63, wid = t >> 6;
    const int wd = wid & 1, wr = wid >> 1;
    const int lr = lane & 15, lh = lane >> 4;

    f32x4 accOG[4] = {};
    f32x4 accOP[4] = {};
    #pragma unroll
    for (int kk = 0; kk < 4; ++kk) {
        bf16x8 ag[4], ao[4], bp, btl;
        #pragma unroll
        for (int m = 0; m < 4; ++m) {
            int dd = wd * 64 + m * 16 + lr;
            int phys = (kk * 4 + lh) ^ (dd & 7);
            ag[m] = *(const bf16x8*)((const char*)wog + dd * 256 + phys * 16);
            ao[m] = *(const bf16x8*)((const char*)wop + dd * 256 + phys * 16);
        }
        {
            int rr = wr * 16 + lr;
            int phys = (kk * 4 + lh) ^ (rr & 7);
            bp  = *(const bf16x8*)((const char*)pt + rr * 256 + phys * 16);
            btl = *(const bf16x8*)((const char*)tt + rr * 256 + phys * 16);
        }
        #pragma unroll
        for (int m = 0; m < 4; ++m) {
            accOG[m] = __builtin_amdgcn_mfma_f32_16x16x32_bf16(ag[m], bp, accOG[m], 0, 0, 0);
            accOP[m] = __builtin_amdgcn_mfma_f32_16x16x32_bf16(ao[m], btl, accOP[m], 0, 0, 0);
        }
    }
    __syncthreads();

    #pragma unroll
    for (int m = 0; m < 4; ++m)
        #pragma unroll
        for (int reg = 0; reg < 4; ++reg) {
            int dd = wd * 64 + m * 16 + lh * 4 + reg;
            float g = accOG[m][reg] + og_b[dd];
            float p = accOP[m][reg] + op_b[dd];
            int rr = wr * 16 + lr;
            ub[rr * 132 + dd] = p * (1.f / (1.f + __expf(-g)));
        }
    __syncthreads();

    {
        int r = t >> 3, q = t & 7;
        const float* prow = pair + (size_t)(row0 + r) * 128 + q * 16;
        float x[16];
        #pragma unroll
        for (int h = 0; h < 4; ++h) {
            f32x4 pv = *(const f32x4*)(prow + h * 4);
            f32x4 uv = *(const f32x4*)(ub + r * 132 + q * 16 + h * 4);
            x[h*4+0] = pv[0] + uv[0]; x[h*4+1] = pv[1] + uv[1];
            x[h*4+2] = pv[2] + uv[2]; x[h*4+3] = pv[3] + uv[3];
        }
        float s1 = 0.f, s2 = 0.f;
        #pragma unroll
        for (int j = 0; j < 16; ++j) { s1 += x[j]; s2 += x[j] * x[j]; }
        s1 += __shfl_xor(s1, 1); s2 += __shfl_xor(s2, 1);
        s1 += __shfl_xor(s1, 2); s2 += __shfl_xor(s2, 2);
        s1 += __shfl_xor(s1, 4); s2 += __shfl_xor(s2, 4);
        float mean = s1 * (1.f / 128.f);
        float rstd = rsqrtf(s2 * (1.f / 128.f) - mean * mean + EPS);
        float* orow = out + (size_t)(row0 + r) * 128 + q * 16;
        #pragma unroll
        for (int h = 0; h < 4; ++h) {
            f32x4 wv = *(const f32x4*)(lnow + q * 16 + h * 4);
            f32x4 bv = *(const f32x4*)(lnob + q * 16 + h * 4);
            f32x4 o;
            #pragma unroll
            for (int e = 0; e < 4; ++e)
                o[e] = (x[h * 4 + e] - mean) * rstd * wv[e] + bv[e];
            *(f32x4*)(orow + h * 4) = o;
        }
    }
}

extern "C" void kernel_launch(void* const* d_in, const int* in_sizes, int n_in,
                              void* d_out, int out_size, void* d_ws, size_t ws_size,
                              hipStream_t stream) {
    const float* pair    = (const float*)d_in[0];
    const float* ln_in_w = (const float*)d_in[1];
    const float* ln_in_b = (const float*)d_in[2];
    const float* lp_w    = (const float*)d_in[3];
    const float* lp_b    = (const float*)d_in[4];
    const float* lg_w    = (const float*)d_in[5];
    const float* lg_b    = (const float*)d_in[6];
    const float* rp_w    = (const float*)d_in[7];
    const float* rp_b    = (const float*)d_in[8];
    const float* rg_w    = (const float*)d_in[9];
    const float* rg_b    = (const float*)d_in[10];
    const float* cn_w    = (const float*)d_in[11];
    const float* cn_b    = (const float*)d_in[12];
    const float* op_w    = (const float*)d_in[13];
    const float* op_b    = (const float*)d_in[14];
    const float* og_w    = (const float*)d_in[15];
    const float* og_b    = (const float*)d_in[16];
    const float* ln_out_w = (const float*)d_in[17];
    const float* ln_out_b = (const float*)d_in[18];

    const size_t HALF = (size_t)128 * NSQ * 2;   // 150,994,944 B
    char* ws = (char*)d_ws;
    bf16* wbf     = (bf16*)ws;
    bf16* right_t = (bf16*)(ws + 196608);
    bf16* tri_ln  = right_t;                      // reuse after K3
    bf16* left_t  = (bf16*)d_out;
    bf16* tri_t   = (bf16*)((char*)d_out + HALF);

    k_convert_w<<<dim3(64, 6), 256, 0, stream>>>(lp_w, lg_w, rp_w, rg_w, op_w, og_w, wbf);
    k_ln_gate2<<<dim3(512), 512, 0, stream>>>(pair, ln_in_w, ln_in_b, wbf,
                                              lp_b, lg_b, rp_b, rg_b, left_t, right_t);
    k_tri<<<dim3(4608), 256, 0, stream>>>(left_t, right_t, tri_t);
    k_cln<<<dim3(NSQ / 256), 256, 0, stream>>>(tri_t, cn_w, cn_b, tri_ln);
    k_final<<<dim3(NSQ / 64), 512, 0, stream>>>(pair, tri_ln, wbf, op_b, og_b,
                                                ln_out_w, ln_out_b, (float*)d_out);
}

// Round 4
// 595.342 us; speedup vs baseline: 1.7097x; 1.1555x over previous
//
#include <hip/hip_runtime.h>

#define N 768
#define D 128
#define NSQ (N*N)
#define EPS 1e-5f

typedef __bf16 bf16;
typedef __bf16 bf16x8 __attribute__((ext_vector_type(8)));
typedef float f32x4 __attribute__((ext_vector_type(4)));

__device__ __forceinline__ void gld16(const void* g, void* l) {
    __builtin_amdgcn_global_load_lds(
        (const __attribute__((address_space(1))) unsigned int*)g,
        (__attribute__((address_space(3))) unsigned int*)l, 16, 0, 0);
}

// ---------------- K0: convert 6 weight matrices fp32 -> bf16 ----------------
__global__ void k_convert_w(const float* __restrict__ lp, const float* __restrict__ lg,
                            const float* __restrict__ rp, const float* __restrict__ rg,
                            const float* __restrict__ op, const float* __restrict__ og,
                            bf16* __restrict__ dst) {
    const float* srcs[6] = {lp, lg, rp, rg, op, og};
    int m = blockIdx.y;
    int i = blockIdx.x * 256 + threadIdx.x;   // 64 blocks x 256 = 16384
    dst[m * 16384 + i] = (bf16)srcs[m][i];
}

// ---------------- K1v2: fused LN + 4 GEMMs + gates, grid-stride -------------
__global__ __launch_bounds__(512, 2) void k_ln_gate2(
    const float* __restrict__ pair, const float* __restrict__ lnw, const float* __restrict__ lnb,
    const bf16* __restrict__ wbf,
    const float* __restrict__ lp_b, const float* __restrict__ lg_b,
    const float* __restrict__ rp_b, const float* __restrict__ rg_b,
    bf16* __restrict__ left_t, bf16* __restrict__ right_t)
{
    __shared__ bf16 zt[2][64 * 128];   // 2 x 16 KB, xor-swizzled 16B chunks

    const int t = threadIdx.x;
    const int lane = t & 63, wid = t >> 6;
    const int side = wid >> 2, dq = wid & 3;      // wave's matrix side + d-quarter
    const int lr = lane & 15, lh = lane >> 4;

    const bf16* wPsrc = wbf + (side ? 2 : 0) * 16384;
    const bf16* wGsrc = wbf + (side ? 3 : 1) * 16384;
    const float* bPp = side ? rp_b : lp_b;
    const float* bGp = side ? rg_b : lg_b;
    bf16* dst = side ? right_t : left_t;

    // A-fragments (weights) held in registers for the whole kernel
    bf16x8 aP[4][2], aG[4][2];
    #pragma unroll
    for (int kk = 0; kk < 4; ++kk)
        #pragma unroll
        for (int m = 0; m < 2; ++m) {
            int rd = dq * 32 + m * 16 + lr;
            aP[kk][m] = *(const bf16x8*)(wPsrc + rd * 128 + (kk * 4 + lh) * 8);
            aG[kk][m] = *(const bf16x8*)(wGsrc + rd * 128 + (kk * 4 + lh) * 8);
        }

    const int r8 = t >> 3, q = t & 7;

    f32x4 lw0 = *(const f32x4*)(lnw + q * 16);
    f32x4 lw1 = *(const f32x4*)(lnw + q * 16 + 4);
    f32x4 lw2 = *(const f32x4*)(lnw + q * 16 + 8);
    f32x4 lw3 = *(const f32x4*)(lnw + q * 16 + 12);
    f32x4 lb0 = *(const f32x4*)(lnb + q * 16);
    f32x4 lb1 = *(const f32x4*)(lnb + q * 16 + 4);
    f32x4 lb2 = *(const f32x4*)(lnb + q * 16 + 8);
    f32x4 lb3 = *(const f32x4*)(lnb + q * 16 + 12);

    const int bid = blockIdx.x, gstride = gridDim.x;

    f32x4 p0, p1, p2, p3;
    {
        const float* prow = pair + (size_t)(bid * 64 + r8) * 128 + q * 16;
        p0 = *(const f32x4*)(prow);
        p1 = *(const f32x4*)(prow + 4);
        p2 = *(const f32x4*)(prow + 8);
        p3 = *(const f32x4*)(prow + 12);
    }

    int buf = 0;
    for (int tile = bid; tile < NSQ / 64; tile += gstride) {
        const int row0 = tile * 64;

        float x[16];
        #pragma unroll
        for (int e = 0; e < 4; ++e) {
            x[e] = p0[e]; x[4 + e] = p1[e]; x[8 + e] = p2[e]; x[12 + e] = p3[e];
        }
        float s1 = 0.f, s2 = 0.f;
        #pragma unroll
        for (int j = 0; j < 16; ++j) { s1 += x[j]; s2 += x[j] * x[j]; }
        s1 += __shfl_xor(s1, 1); s2 += __shfl_xor(s2, 1);
        s1 += __shfl_xor(s1, 2); s2 += __shfl_xor(s2, 2);
        s1 += __shfl_xor(s1, 4); s2 += __shfl_xor(s2, 4);
        float mean = s1 * (1.f / 128.f);
        float rstd = rsqrtf(s2 * (1.f / 128.f) - mean * mean + EPS);

        bf16x8 pk0, pk1;
        #pragma unroll
        for (int e = 0; e < 4; ++e) {
            pk0[e]     = (bf16)((x[e]      - mean) * rstd * lw0[e] + lb0[e]);
            pk0[4 + e] = (bf16)((x[4 + e]  - mean) * rstd * lw1[e] + lb1[e]);
            pk1[e]     = (bf16)((x[8 + e]  - mean) * rstd * lw2[e] + lb2[e]);
            pk1[4 + e] = (bf16)((x[12 + e] - mean) * rstd * lw3[e] + lb3[e]);
        }
        {
            char* zb = (char*)&zt[buf][0];
            *(bf16x8*)(zb + r8 * 256 + ((q * 2)     ^ (r8 & 7)) * 16) = pk0;
            *(bf16x8*)(zb + r8 * 256 + ((q * 2 + 1) ^ (r8 & 7)) * 16) = pk1;
        }
        __syncthreads();

        int nt = tile + gstride;
        if (nt < NSQ / 64) {
            const float* prow = pair + (size_t)(nt * 64 + r8) * 128 + q * 16;
            p0 = *(const f32x4*)(prow);
            p1 = *(const f32x4*)(prow + 4);
            p2 = *(const f32x4*)(prow + 8);
            p3 = *(const f32x4*)(prow + 12);
        }

        f32x4 accP[2][4] = {};
        f32x4 accG[2][4] = {};
        const char* zb = (const char*)&zt[buf][0];
        #pragma unroll
        for (int kk = 0; kk < 4; ++kk) {
            bf16x8 bz[4];
            #pragma unroll
            for (int n = 0; n < 4; ++n) {
                int rz = n * 16 + lr;
                bz[n] = *(const bf16x8*)(zb + rz * 256 + (((kk * 4 + lh)) ^ (rz & 7)) * 16);
            }
            #pragma unroll
            for (int m = 0; m < 2; ++m)
                #pragma unroll
                for (int n = 0; n < 4; ++n) {
                    accP[m][n] = __builtin_amdgcn_mfma_f32_16x16x32_bf16(aP[kk][m], bz[n], accP[m][n], 0, 0, 0);
                    accG[m][n] = __builtin_amdgcn_mfma_f32_16x16x32_bf16(aG[kk][m], bz[n], accG[m][n], 0, 0, 0);
                }
        }

        #pragma unroll
        for (int m = 0; m < 2; ++m) {
            f32x4 vbP = *(const f32x4*)(bPp + dq * 32 + m * 16 + lh * 4);
            f32x4 vbG = *(const f32x4*)(bGp + dq * 32 + m * 16 + lh * 4);
            #pragma unroll
            for (int reg = 0; reg < 4; ++reg) {
                int d = dq * 32 + m * 16 + lh * 4 + reg;
                #pragma unroll
                for (int n = 0; n < 4; ++n) {
                    float g = accG[m][n][reg] + vbG[reg];
                    float p = accP[m][n][reg] + vbP[reg];
                    float val = p * (1.f / (1.f + __expf(-g)));
                    dst[(size_t)d * NSQ + row0 + n * 16 + lr] = (bf16)val;
                }
            }
        }
        buf ^= 1;
        __syncthreads();
    }
}

// ---------------- K3v2: tri_t[d] = L_d @ R_d^T, XCD-pinned batch ------------
__global__ __launch_bounds__(256, 4) void k_tri(
    const bf16* __restrict__ left_t, const bf16* __restrict__ right_t, bf16* __restrict__ tri_t)
{
    __shared__ bf16 at[2][128 * 32];
    __shared__ bf16 bt[2][128 * 32];
    const int t = threadIdx.x;
    const int b = blockIdx.x;
    const int xcd = b & 7;
    const int s = b >> 3;
    const int d = xcd * 16 + s / 36;
    const int tile = s % 36;
    const int ti = tile / 6, tj = tile % 6;   // tj fastest: consecutive blocks share A panel
    const bf16* A = left_t + (size_t)d * NSQ;
    const bf16* B = right_t + (size_t)d * NSQ;
    const int i0 = ti * 128, j0 = tj * 128;

    auto stage = [&](int buf, int kt) {
        int k0 = kt * 32;
        #pragma unroll
        for (int c = 0; c < 2; ++c) {
            int sl = c * 256 + t;           // 512 slots of 16B per tile
            int r = sl >> 2, cp = sl & 3, cl = cp ^ ((r >> 1) & 3);
            gld16(A + (size_t)(i0 + r) * 768 + k0 + cl * 8, (char*)at[buf] + sl * 16);
            gld16(B + (size_t)(j0 + r) * 768 + k0 + cl * 8, (char*)bt[buf] + sl * 16);
        }
    };

    const int lane = t & 63, wid = t >> 6;
    const int wr = wid >> 1, wc = wid & 1;
    const int lr = lane & 15, lh = lane >> 4;

    f32x4 acc[4][4] = {};

    stage(0, 0);
    __syncthreads();
    for (int kt = 0; kt < 24; ++kt) {
        if (kt < 23) stage((kt + 1) & 1, kt + 1);
        const bf16* ab = at[kt & 1];
        const bf16* bb = bt[kt & 1];
        bf16x8 af[4], bff[4];
        #pragma unroll
        for (int m = 0; m < 4; ++m) {
            int r = wr * 64 + m * 16 + lr;
            int phys = lh ^ ((r >> 1) & 3);
            af[m] = *(const bf16x8*)((const char*)ab + r * 64 + phys * 16);
        }
        #pragma unroll
        for (int n = 0; n < 4; ++n) {
            int r = wc * 64 + n * 16 + lr;
            int phys = lh ^ ((r >> 1) & 3);
            bff[n] = *(const bf16x8*)((const char*)bb + r * 64 + phys * 16);
        }
        #pragma unroll
        for (int m = 0; m < 4; ++m)
            #pragma unroll
            for (int n = 0; n < 4; ++n)
                acc[m][n] = __builtin_amdgcn_mfma_f32_16x16x32_bf16(af[m], bff[n], acc[m][n], 0, 0, 0);
        __syncthreads();
    }

    bf16* C = tri_t + (size_t)d * NSQ;
    #pragma unroll
    for (int m = 0; m < 4; ++m)
        #pragma unroll
        for (int n = 0; n < 4; ++n)
            #pragma unroll
            for (int reg = 0; reg < 4; ++reg) {
                int ri = i0 + wr * 64 + m * 16 + lh * 4 + reg;
                int cj = j0 + wc * 64 + n * 16 + lr;
                C[(size_t)ri * 768 + cj] = (bf16)acc[m][n][reg];
            }
}

// ---------------- K4v2: LN over d, single global read -----------------------
__global__ __launch_bounds__(256, 2) void k_cln(
    const bf16* __restrict__ tri_t, const float* __restrict__ cnw, const float* __restrict__ cnb,
    bf16* __restrict__ tri_ln)
{
    __shared__ bf16 tile[256 * 128];   // 64 KB raw values
    __shared__ float mrs[256][2];      // mean, rstd
    const int t = threadIdx.x;
    const size_t ij = (size_t)blockIdx.x * 256 + t;
    float s1 = 0.f, s2 = 0.f;
    for (int dc = 0; dc < 16; ++dc) {
        bf16x8 pk;
        #pragma unroll
        for (int e = 0; e < 8; ++e) {
            int dd = dc * 8 + e;
            bf16 raw = tri_t[(size_t)dd * NSQ + ij];
            float v = (float)raw;
            s1 += v; s2 += v * v;
            pk[e] = raw;
        }
        *(bf16x8*)((char*)tile + t * 256 + (dc ^ (t & 7)) * 16) = pk;
    }
    float mean = s1 * (1.f / 128.f);
    float rstd = rsqrtf(s2 * (1.f / 128.f) - mean * mean + EPS);
    mrs[t][0] = mean; mrs[t][1] = rstd;
    __syncthreads();
    const size_t ij0 = (size_t)blockIdx.x * 256;
    #pragma unroll
    for (int c = 0; c < 16; ++c) {
        int sl = c * 256 + t;
        int rl = sl >> 4, cp = sl & 15, cl = cp ^ (rl & 7);
        bf16x8 raw = *(const bf16x8*)((const char*)tile + rl * 256 + cp * 16);
        float m = mrs[rl][0], r = mrs[rl][1];
        f32x4 w0 = *(const f32x4*)(cnw + cl * 8);
        f32x4 w1 = *(const f32x4*)(cnw + cl * 8 + 4);
        f32x4 b0 = *(const f32x4*)(cnb + cl * 8);
        f32x4 b1 = *(const f32x4*)(cnb + cl * 8 + 4);
        bf16x8 o;
        #pragma unroll
        for (int e = 0; e < 4; ++e) {
            o[e]     = (bf16)(((float)raw[e]     - m) * r * w0[e] + b0[e]);
            o[4 + e] = (bf16)(((float)raw[4 + e] - m) * r * w1[e] + b1[e]);
        }
        *(bf16x8*)(tri_ln + (ij0 + rl) * 128 + cl * 8) = o;
    }
}

// ---------------- K5v2: persistent fused out-gate + residual + final LN -----
// 512 blocks x 512 threads grid-stride 9216 row-tiles of 64. og/op weight
// fragments in registers. LDS: zt(raw pair bf16, 16K) + tt[2](tri_ln, 32K)
// + ub(fp32 exchange, 33K) = 83K -> 1 block/CU. 2 barriers/tile.
__global__ __launch_bounds__(512, 2) void k_final2(
    const float* __restrict__ pair, const bf16* __restrict__ tri_ln,
    const bf16* __restrict__ wbf,
    const float* __restrict__ op_b, const float* __restrict__ og_b,
    const float* __restrict__ lnow, const float* __restrict__ lnob,
    float* __restrict__ out)
{
    __shared__ bf16 zt[64 * 128];       // raw pair bf16, swizzled
    __shared__ bf16 tt[2][64 * 128];    // tri_ln, swizzled, double-buffered
    __shared__ float ub[64 * 132];      // gated output exchange

    const int t = threadIdx.x;
    const int lane = t & 63, wid = t >> 6;
    const int dq = wid & 3, wh = wid >> 2;   // d-quarter, row-half
    const int lr = lane & 15, lh = lane >> 4;

    const bf16* opsrc = wbf + 4 * 16384;
    const bf16* ogsrc = wbf + 5 * 16384;

    // weight A-fragments in registers (rows = output channel dd)
    bf16x8 aOG[4][2], aOP[4][2];
    #pragma unroll
    for (int kk = 0; kk < 4; ++kk)
        #pragma unroll
        for (int m = 0; m < 2; ++m) {
            int rd = dq * 32 + m * 16 + lr;
            aOG[kk][m] = *(const bf16x8*)(ogsrc + rd * 128 + (kk * 4 + lh) * 8);
            aOP[kk][m] = *(const bf16x8*)(opsrc + rd * 128 + (kk * 4 + lh) * 8);
        }
    f32x4 vbOG[2], vbOP[2];
    #pragma unroll
    for (int m = 0; m < 2; ++m) {
        vbOG[m] = *(const f32x4*)(og_b + dq * 32 + m * 16 + lh * 4);
        vbOP[m] = *(const f32x4*)(op_b + dq * 32 + m * 16 + lh * 4);
    }

    const int r8 = t >> 3, q = t & 7;
    f32x4 lw0 = *(const f32x4*)(lnow + q * 16);
    f32x4 lw1 = *(const f32x4*)(lnow + q * 16 + 4);
    f32x4 lw2 = *(const f32x4*)(lnow + q * 16 + 8);
    f32x4 lw3 = *(const f32x4*)(lnow + q * 16 + 12);
    f32x4 lb0 = *(const f32x4*)(lnob + q * 16);
    f32x4 lb1 = *(const f32x4*)(lnob + q * 16 + 4);
    f32x4 lb2 = *(const f32x4*)(lnob + q * 16 + 8);
    f32x4 lb3 = *(const f32x4*)(lnob + q * 16 + 12);

    const int bid = blockIdx.x, gstride = gridDim.x;

    auto stage_tt = [&](int buf, int tile) {
        const int row0 = tile * 64;
        #pragma unroll
        for (int c = 0; c < 2; ++c) {
            int s = c * 512 + t;                 // 1024 slots of 16B
            int r = s >> 4, cp = s & 15, cl = cp ^ (r & 7);
            gld16(tri_ln + (size_t)(row0 + r) * 128 + cl * 8, (char*)tt[buf] + s * 16);
        }
    };

    // prologue: pair regs + tt[0] for first tile
    f32x4 pA0, pA1, pA2, pA3;
    {
        const float* prow = pair + (size_t)(bid * 64 + r8) * 128 + q * 16;
        pA0 = *(const f32x4*)(prow);
        pA1 = *(const f32x4*)(prow + 4);
        pA2 = *(const f32x4*)(prow + 8);
        pA3 = *(const f32x4*)(prow + 12);
    }
    stage_tt(0, bid);

    int buf = 0;
    for (int tile = bid; tile < NSQ / 64; tile += gstride) {
        const int row0 = tile * 64;

        // write raw-pair bf16 tile (swizzled) from registers
        {
            bf16x8 pk0, pk1;
            #pragma unroll
            for (int e = 0; e < 4; ++e) {
                pk0[e]     = (bf16)pA0[e];
                pk0[4 + e] = (bf16)pA1[e];
                pk1[e]     = (bf16)pA2[e];
                pk1[4 + e] = (bf16)pA3[e];
            }
            char* zb = (char*)zt;
            *(bf16x8*)(zb + r8 * 256 + ((q * 2)     ^ (r8 & 7)) * 16) = pk0;
            *(bf16x8*)(zb + r8 * 256 + ((q * 2 + 1) ^ (r8 & 7)) * 16) = pk1;
        }
        __syncthreads();   // A: zt ready, tt[buf] staged (vmcnt drained)

        const int nt = tile + gstride;
        if (nt < NSQ / 64) stage_tt(buf ^ 1, nt);

        // prefetch next pair tile into regs (hidden under MFMA)
        f32x4 pB0 = pA0, pB1 = pA1, pB2 = pA2, pB3 = pA3;
        if (nt < NSQ / 64) {
            const float* prow = pair + (size_t)(nt * 64 + r8) * 128 + q * 16;
            pB0 = *(const f32x4*)(prow);
            pB1 = *(const f32x4*)(prow + 4);
            pB2 = *(const f32x4*)(prow + 8);
            pB3 = *(const f32x4*)(prow + 12);
        }

        // dual GEMM: OG gate from zt (raw pair), OP proj from tt (tri_ln)
        f32x4 accOG[2][2] = {};
        f32x4 accOP[2][2] = {};
        const char* zb = (const char*)zt;
        const char* tb = (const char*)tt[buf];
        #pragma unroll
        for (int kk = 0; kk < 4; ++kk) {
            bf16x8 bzp[2], bzt[2];
            #pragma unroll
            for (int n = 0; n < 2; ++n) {
                int rz = wh * 32 + n * 16 + lr;
                int phys = (kk * 4 + lh) ^ (rz & 7);
                bzp[n] = *(const bf16x8*)(zb + rz * 256 + phys * 16);
                bzt[n] = *(const bf16x8*)(tb + rz * 256 + phys * 16);
            }
            #pragma unroll
            for (int m = 0; m < 2; ++m)
                #pragma unroll
                for (int n = 0; n < 2; ++n) {
                    accOG[m][n] = __builtin_amdgcn_mfma_f32_16x16x32_bf16(aOG[kk][m], bzp[n], accOG[m][n], 0, 0, 0);
                    accOP[m][n] = __builtin_amdgcn_mfma_f32_16x16x32_bf16(aOP[kk][m], bzt[n], accOP[m][n], 0, 0, 0);
                }
        }

        // gate + write ub
        #pragma unroll
        for (int m = 0; m < 2; ++m)
            #pragma unroll
            for (int n = 0; n < 2; ++n) {
                int rr = wh * 32 + n * 16 + lr;
                f32x4 v;
                #pragma unroll
                for (int reg = 0; reg < 4; ++reg) {
                    float g = accOG[m][n][reg] + vbOG[m][reg];
                    float p = accOP[m][n][reg] + vbOP[m][reg];
                    v[reg] = p * (1.f / (1.f + __expf(-g)));
                }
                *(f32x4*)(ub + rr * 132 + dq * 32 + m * 16 + lh * 4) = v;
            }
        __syncthreads();   // B: ub ready, zt/tt reads done

        // residual + final LN + store
        {
            float x[16];
            const float* ur = ub + r8 * 132 + q * 16;
            f32x4 u0 = *(const f32x4*)(ur);
            f32x4 u1 = *(const f32x4*)(ur + 4);
            f32x4 u2 = *(const f32x4*)(ur + 8);
            f32x4 u3 = *(const f32x4*)(ur + 12);
            #pragma unroll
            for (int e = 0; e < 4; ++e) {
                x[e]      = pA0[e] + u0[e];
                x[4 + e]  = pA1[e] + u1[e];
                x[8 + e]  = pA2[e] + u2[e];
                x[12 + e] = pA3[e] + u3[e];
            }
            float s1 = 0.f, s2 = 0.f;
            #pragma unroll
            for (int j = 0; j < 16; ++j) { s1 += x[j]; s2 += x[j] * x[j]; }
            s1 += __shfl_xor(s1, 1); s2 += __shfl_xor(s2, 1);
            s1 += __shfl_xor(s1, 2); s2 += __shfl_xor(s2, 2);
            s1 += __shfl_xor(s1, 4); s2 += __shfl_xor(s2, 4);
            float mean = s1 * (1.f / 128.f);
            float rstd = rsqrtf(s2 * (1.f / 128.f) - mean * mean + EPS);
            float* orow = out + (size_t)(row0 + r8) * 128 + q * 16;
            f32x4 o0, o1, o2, o3;
            #pragma unroll
            for (int e = 0; e < 4; ++e) {
                o0[e] = (x[e]      - mean) * rstd * lw0[e] + lb0[e];
                o1[e] = (x[4 + e]  - mean) * rstd * lw1[e] + lb1[e];
                o2[e] = (x[8 + e]  - mean) * rstd * lw2[e] + lb2[e];
                o3[e] = (x[12 + e] - mean) * rstd * lw3[e] + lb3[e];
            }
            *(f32x4*)(orow)      = o0;
            *(f32x4*)(orow + 4)  = o1;
            *(f32x4*)(orow + 8)  = o2;
            *(f32x4*)(orow + 12) = o3;
        }

        pA0 = pB0; pA1 = pB1; pA2 = pB2; pA3 = pB3;
        buf ^= 1;
    }
}

extern "C" void kernel_launch(void* const* d_in, const int* in_sizes, int n_in,
                              void* d_out, int out_size, void* d_ws, size_t ws_size,
                              hipStream_t stream) {
    const float* pair    = (const float*)d_in[0];
    const float* ln_in_w = (const float*)d_in[1];
    const float* ln_in_b = (const float*)d_in[2];
    const float* lp_w    = (const float*)d_in[3];
    const float* lp_b    = (const float*)d_in[4];
    const float* lg_w    = (const float*)d_in[5];
    const float* lg_b    = (const float*)d_in[6];
    const float* rp_w    = (const float*)d_in[7];
    const float* rp_b    = (const float*)d_in[8];
    const float* rg_w    = (const float*)d_in[9];
    const float* rg_b    = (const float*)d_in[10];
    const float* cn_w    = (const float*)d_in[11];
    const float* cn_b    = (const float*)d_in[12];
    const float* op_w    = (const float*)d_in[13];
    const float* op_b    = (const float*)d_in[14];
    const float* og_w    = (const float*)d_in[15];
    const float* og_b    = (const float*)d_in[16];
    const float* ln_out_w = (const float*)d_in[17];
    const float* ln_out_b = (const float*)d_in[18];

    const size_t HALF = (size_t)128 * NSQ * 2;   // 150,994,944 B
    char* ws = (char*)d_ws;
    bf16* wbf     = (bf16*)ws;
    bf16* right_t = (bf16*)(ws + 196608);
    bf16* tri_ln  = right_t;                      // reuse after K3
    bf16* left_t  = (bf16*)d_out;
    bf16* tri_t   = (bf16*)((char*)d_out + HALF);

    k_convert_w<<<dim3(64, 6), 256, 0, stream>>>(lp_w, lg_w, rp_w, rg_w, op_w, og_w, wbf);
    k_ln_gate2<<<dim3(512), 512, 0, stream>>>(pair, ln_in_w, ln_in_b, wbf,
                                              lp_b, lg_b, rp_b, rg_b, left_t, right_t);
    k_tri<<<dim3(4608), 256, 0, stream>>>(left_t, right_t, tri_t);
    k_cln<<<dim3(NSQ / 256), 256, 0, stream>>>(tri_t, cn_w, cn_b, tri_ln);
    k_final2<<<dim3(512), 512, 0, stream>>>(pair, tri_ln, wbf, op_b, og_b,
                                            ln_out_w, ln_out_b, (float*)d_out);
}